// Round 1
// baseline (2736.433 us; speedup 1.0000x reference)
//
#include <hip/hip_runtime.h>

#define EPS 1e-6f
#define LN_EPS 1e-5f

typedef unsigned short u16;
typedef unsigned int u32;

__device__ __forceinline__ float bf2f(u16 u) {
  return __uint_as_float(((u32)u) << 16);
}
__device__ __forceinline__ u16 f2bf(float f) {
  u32 x = __float_as_uint(f);
  x += 0x7fffu + ((x >> 16) & 1u);
  return (u16)(x >> 16);
}

// ---------------------------------------------------------------- init slots
// slots[b,k,s] = w[k,s] * (1 + sigma * z[b,k,s])
__global__ void init_slots_kernel(const float* __restrict__ w,
                                  const float* __restrict__ z,
                                  const float* __restrict__ sigma,
                                  float* __restrict__ slots) {
  int i = blockIdx.x * 256 + threadIdx.x;  // < 90112
  int s = i & 255;
  int k = (i >> 8) % 11;
  float wv = w[k * 256 + s];
  slots[i] = wv + z[i] * sigma[0] * wv;
}

// ------------------------------------------------------- transpose W_ih/W_hh
__global__ void transpose_kernel(const float* __restrict__ wih,
                                 const float* __restrict__ whh,
                                 float* __restrict__ wihT,
                                 float* __restrict__ whhT) {
  int i = blockIdx.x * 256 + threadIdx.x;
  if (i < 196608) {
    int j = i >> 8, d = i & 255;
    wihT[d * 768 + j] = wih[i];
  } else if (i < 393216) {
    int e = i - 196608;
    int j = e >> 8, d = e & 255;
    whhT[d * 768 + j] = whh[e];
  }
}

// ------------------------------------------------------------- zero scratch
__global__ void zero_kernel(float* __restrict__ sums, float* __restrict__ upd) {
  int i = blockIdx.x * 256 + threadIdx.x;  // grid 352*256 = 90112
  if (i < 352) sums[i] = 0.f;
  upd[i] = 0.f;
}

// ------------------------------------------------- per-row LN stats (w=256)
__global__ void stats_kernel(const float* __restrict__ x,
                             float* __restrict__ mean, float* __restrict__ rstd,
                             int rows) {
  int wave = threadIdx.x >> 6;
  int lane = threadIdx.x & 63;
  int row = blockIdx.x * 4 + wave;
  if (row >= rows) return;
  float4 v = *(const float4*)(x + (long)row * 256 + lane * 4);
  float s = v.x + v.y + v.z + v.w;
  float s2 = v.x * v.x + v.y * v.y + v.z * v.z + v.w * v.w;
  #pragma unroll
  for (int off = 32; off > 0; off >>= 1) {
    s += __shfl_xor(s, off);
    s2 += __shfl_xor(s2, off);
  }
  if (lane == 0) {
    float mu = s * (1.0f / 256.0f);
    float var = s2 * (1.0f / 256.0f) - mu * mu;
    mean[row] = mu;
    rstd[row] = rsqrtf(var + LN_EPS);
  }
}

// ------------------------------------------------------------- generic GEMM
// C[M,Nc] = act( LN(A)[M,Kd] @ W[Kd,Nc] + bias ) + resid
// LN applied per A-row if mean != null; gamma/beta if gamma != null.
// Output fp32 (Cf) or bf16 (Cb).
__global__ __launch_bounds__(256) void gemm_ln(
    const float* __restrict__ A, const float* __restrict__ W,
    float* __restrict__ Cf, u16* __restrict__ Cb,
    int M, int Nc, int Kd,
    const float* __restrict__ mean, const float* __restrict__ rstd,
    const float* __restrict__ gamma, const float* __restrict__ beta,
    const float* __restrict__ bias, const float* __restrict__ resid, int relu) {
  __shared__ float As[32][68];  // +4 pad: 4-way max on store, conflict-free read
  __shared__ float Bs[32][64];
  int t = threadIdx.x;
  int tx = t & 15, ty = t >> 4;
  int rowbase = blockIdx.x * 64;
  int colbase = blockIdx.y * 64;
  float acc[4][4] = {};
  int ktiles = Kd >> 5;
  for (int kt = 0; kt < ktiles; ++kt) {
    #pragma unroll
    for (int i = 0; i < 8; ++i) {
      int e = t + i * 256;
      int m = e >> 5, kk = e & 31;
      int row = rowbase + m;
      int f = kt * 32 + kk;
      float val = 0.f;
      if (row < M) {
        val = A[(long)row * Kd + f];
        if (mean) val = (val - mean[row]) * rstd[row];
        if (gamma) val = val * gamma[f] + beta[f];
      }
      As[kk][m] = val;
    }
    #pragma unroll
    for (int i = 0; i < 8; ++i) {
      int e = t + i * 256;
      int kk = e >> 6, j = e & 63;
      Bs[kk][j] = W[(long)(kt * 32 + kk) * Nc + colbase + j];
    }
    __syncthreads();
    #pragma unroll
    for (int kk = 0; kk < 32; ++kk) {
      float4 a4 = *(const float4*)&As[kk][ty * 4];
      float4 b4 = *(const float4*)&Bs[kk][tx * 4];
      float av[4] = {a4.x, a4.y, a4.z, a4.w};
      float bv[4] = {b4.x, b4.y, b4.z, b4.w};
      #pragma unroll
      for (int i = 0; i < 4; ++i)
        #pragma unroll
        for (int j = 0; j < 4; ++j) acc[i][j] += av[i] * bv[j];
    }
    __syncthreads();
  }
  #pragma unroll
  for (int i = 0; i < 4; ++i) {
    int row = rowbase + ty * 4 + i;
    if (row >= M) continue;
    int c0 = colbase + tx * 4;
    float v[4];
    #pragma unroll
    for (int j = 0; j < 4; ++j) {
      float val = acc[i][j];
      if (bias) val += bias[c0 + j];
      if (relu) val = fmaxf(val, 0.f);
      if (resid) val += resid[(long)row * Nc + c0 + j];
      v[j] = val;
    }
    if (Cb) {
      ushort4 u;
      u.x = f2bf(v[0]); u.y = f2bf(v[1]); u.z = f2bf(v[2]); u.w = f2bf(v[3]);
      *(ushort4*)&Cb[(long)row * Nc + c0] = u;
    } else {
      float4 fv = make_float4(v[0], v[1], v[2], v[3]);
      *(float4*)&Cf[(long)row * Nc + c0] = fv;
    }
  }
}

// -------------------------------------------------------- attention softmax
// Per (b,n): logits[kk] = (q[b,kk,:] . k[b,n,:]) / 16; softmax over kk (11);
// write attn[b,kk,n]; atomically accumulate sums[b,kk] = sum_n attn.
// Block: 128 threads = 32 n x 4 f-quarters. Grid: (4096/32, B).
__global__ __launch_bounds__(128) void attn_kernel(
    const float* __restrict__ q, const u16* __restrict__ kb,
    float* __restrict__ attn, float* __restrict__ sums) {
  __shared__ float qs[11 * 256];
  __shared__ float ks[32 * 260];  // stride 260 -> conflict-free b128 reads
  int b = blockIdx.y;
  int n0 = blockIdx.x * 32;
  int t = threadIdx.x;
  #pragma unroll
  for (int i = 0; i < 22; ++i) {
    int e = t + i * 128;
    qs[e] = q[b * 2816 + e];
  }
  const ushort4* kbase = (const ushort4*)(kb + ((long)b * 4096 + n0) * 256);
  #pragma unroll
  for (int i = 0; i < 16; ++i) {
    int idx4 = t + i * 128;         // 2048 ushort4 total
    int r = idx4 >> 6, f4 = idx4 & 63;
    ushort4 u = kbase[r * 64 + f4];
    float4 fv = make_float4(bf2f(u.x), bf2f(u.y), bf2f(u.z), bf2f(u.w));
    *(float4*)&ks[r * 260 + f4 * 4] = fv;
  }
  __syncthreads();
  int nl = t >> 2, j = t & 3;
  float acc[11];
  #pragma unroll
  for (int kk = 0; kk < 11; ++kk) acc[kk] = 0.f;
  const float* krow = &ks[nl * 260 + j * 64];
  #pragma unroll
  for (int ii = 0; ii < 16; ++ii) {
    float4 kv = *(const float4*)&krow[ii * 4];
    #pragma unroll
    for (int kk = 0; kk < 11; ++kk) {
      float4 qv = *(const float4*)&qs[kk * 256 + j * 64 + ii * 4];
      acc[kk] += kv.x * qv.x + kv.y * qv.y + kv.z * qv.z + kv.w * qv.w;
    }
  }
  #pragma unroll
  for (int kk = 0; kk < 11; ++kk) {
    acc[kk] += __shfl_xor(acc[kk], 1);
    acc[kk] += __shfl_xor(acc[kk], 2);
    acc[kk] *= 0.0625f;  // 256^-0.5
  }
  float mx = acc[0];
  #pragma unroll
  for (int kk = 1; kk < 11; ++kk) mx = fmaxf(mx, acc[kk]);
  float ssum = 0.f;
  #pragma unroll
  for (int kk = 0; kk < 11; ++kk) {
    acc[kk] = expf(acc[kk] - mx);
    ssum += acc[kk];
  }
  float inv = 1.0f / ssum;
  int n = n0 + nl;
  for (int kk = j; kk < 11; kk += 4) {
    float val = acc[kk] * inv;
    attn[((long)b * 11 + kk) * 4096 + n] = val;
    float v2 = val;
    v2 += __shfl_xor(v2, 4);
    v2 += __shfl_xor(v2, 8);
    v2 += __shfl_xor(v2, 16);
    v2 += __shfl_xor(v2, 32);
    if (((t >> 2) & 15) == 0) atomicAdd(&sums[b * 11 + kk], v2);
  }
}

// ---------------------------------------------------------------- updates
// updates[b,kk,s] += (1/(sums+eps)) * sum_{n in chunk} attn[b,kk,n]*v[b,n,s]
// Block 128 threads (thread = s-pair). Grid: (16 n-chunks of 256, B).
__global__ __launch_bounds__(128) void updates_kernel(
    const float* __restrict__ attn, const u16* __restrict__ vb,
    const float* __restrict__ sums, float* __restrict__ upd) {
  __shared__ float as_[11 * 256];
  int b = blockIdx.y;
  int n0 = blockIdx.x * 256;
  int t = threadIdx.x;
  #pragma unroll
  for (int i = 0; i < 22; ++i) {
    int e = t + i * 128;
    int kk = e >> 8, n = e & 255;
    as_[e] = attn[((long)b * 11 + kk) * 4096 + n0 + n];
  }
  __syncthreads();
  float2 acc[11];
  #pragma unroll
  for (int kk = 0; kk < 11; ++kk) acc[kk] = make_float2(0.f, 0.f);
  const ushort2* vbase = (const ushort2*)(vb + ((long)b * 4096 + n0) * 256);
  for (int n4 = 0; n4 < 256; n4 += 4) {
    ushort2 u0 = vbase[(n4 + 0) * 128 + t];
    ushort2 u1 = vbase[(n4 + 1) * 128 + t];
    ushort2 u2 = vbase[(n4 + 2) * 128 + t];
    ushort2 u3 = vbase[(n4 + 3) * 128 + t];
    float v0x = bf2f(u0.x), v0y = bf2f(u0.y);
    float v1x = bf2f(u1.x), v1y = bf2f(u1.y);
    float v2x = bf2f(u2.x), v2y = bf2f(u2.y);
    float v3x = bf2f(u3.x), v3y = bf2f(u3.y);
    #pragma unroll
    for (int kk = 0; kk < 11; ++kk) {
      float4 a4 = *(const float4*)&as_[kk * 256 + n4];
      acc[kk].x += a4.x * v0x + a4.y * v1x + a4.z * v2x + a4.w * v3x;
      acc[kk].y += a4.x * v0y + a4.y * v1y + a4.z * v2y + a4.w * v3y;
    }
  }
  #pragma unroll
  for (int kk = 0; kk < 11; ++kk) {
    float scale = 1.0f / (sums[b * 11 + kk] + EPS);
    atomicAdd(&upd[((long)b * 11 + kk) * 256 + 2 * t], acc[kk].x * scale);
    atomicAdd(&upd[((long)b * 11 + kk) * 256 + 2 * t + 1], acc[kk].y * scale);
  }
}

// --------------------------------------------------------------- GRU gates
__global__ void gru_kernel(const float* __restrict__ gi,
                           const float* __restrict__ gh,
                           const float* __restrict__ h,
                           float* __restrict__ out) {
  int row = blockIdx.x;  // 352
  int s = threadIdx.x;   // 256
  float ir = gi[row * 768 + s];
  float iz = gi[row * 768 + 256 + s];
  float in_ = gi[row * 768 + 512 + s];
  float hr = gh[row * 768 + s];
  float hz = gh[row * 768 + 256 + s];
  float hn = gh[row * 768 + 512 + s];
  float hv = h[row * 256 + s];
  float r = 1.f / (1.f + expf(-(ir + hr)));
  float zg = 1.f / (1.f + expf(-(iz + hz)));
  float n = tanhf(in_ + r * hn);
  out[row * 256 + s] = (1.f - zg) * n + zg * hv;
}

// ---------------------------------------------------------------- launcher
extern "C" void kernel_launch(void* const* d_in, const int* in_sizes, int n_in,
                              void* d_out, int out_size, void* d_ws,
                              size_t ws_size, hipStream_t stream) {
  const float* features = (const float*)d_in[0];
  const float* sigma = (const float*)d_in[1];
  const float* z = (const float*)d_in[2];
  const float* slots_init_w = (const float*)d_in[3];
  const float* gf = (const float*)d_in[4];
  const float* bf = (const float*)d_in[5];
  const float* gs = (const float*)d_in[6];
  const float* bs = (const float*)d_in[7];
  const float* gm = (const float*)d_in[8];
  const float* bm = (const float*)d_in[9];
  const float* Wk = (const float*)d_in[10];
  const float* Wv = (const float*)d_in[11];
  const float* Wq = (const float*)d_in[12];
  const float* W_ih = (const float*)d_in[13];
  const float* W_hh = (const float*)d_in[14];
  const float* b_ih = (const float*)d_in[15];
  const float* b_hh = (const float*)d_in[16];
  const float* W1 = (const float*)d_in[17];
  const float* b1 = (const float*)d_in[18];
  const float* W2 = (const float*)d_in[19];
  const float* b2 = (const float*)d_in[20];

  float* ws = (float*)d_ws;
  size_t o = 0;
  float* meanF = ws + o; o += 131072;
  float* rstdF = ws + o; o += 131072;
  u16* kbuf = (u16*)(ws + o); o += 16777216;  // 33554432 bf16
  u16* vbuf = (u16*)(ws + o); o += 16777216;
  float* wihT = ws + o; o += 196608;
  float* whhT = ws + o; o += 196608;
  float* slots = ws + o; o += 90112;
  float* sg = ws + o; o += 90112;
  float* qbuf = ws + o; o += 90112;
  float* gibuf = ws + o; o += 270336;
  float* ghbuf = ws + o; o += 270336;
  float* h1buf = ws + o; o += 360448;
  float* upd = ws + o; o += 90112;
  float* sums = ws + o; o += 352;
  float* meanS = ws + o; o += 352;
  float* rstdS = ws + o; o += 352;

  float* out_slots = (float*)d_out;
  float* out_attn = (float*)d_out + 90112;

  init_slots_kernel<<<352, 256, 0, stream>>>(slots_init_w, z, sigma, slots);
  transpose_kernel<<<1536, 256, 0, stream>>>(W_ih, W_hh, wihT, whhT);
  stats_kernel<<<32768, 256, 0, stream>>>(features, meanF, rstdF, 131072);
  // k and v projections (fused LN), bf16 outputs
  gemm_ln<<<dim3(2048, 4), 256, 0, stream>>>(features, Wk, nullptr, kbuf,
      131072, 256, 256, meanF, rstdF, gf, bf, nullptr, nullptr, 0);
  gemm_ln<<<dim3(2048, 4), 256, 0, stream>>>(features, Wv, nullptr, vbuf,
      131072, 256, 256, meanF, rstdF, gf, bf, nullptr, nullptr, 0);

  for (int it = 0; it < 3; ++it) {
    stats_kernel<<<88, 256, 0, stream>>>(slots, meanS, rstdS, 352);
    gemm_ln<<<dim3(6, 4), 256, 0, stream>>>(slots, Wq, qbuf, nullptr,
        352, 256, 256, meanS, rstdS, gs, bs, nullptr, nullptr, 0);
    zero_kernel<<<352, 256, 0, stream>>>(sums, upd);
    attn_kernel<<<dim3(128, 32), 128, 0, stream>>>(qbuf, kbuf, out_attn, sums);
    updates_kernel<<<dim3(16, 32), 128, 0, stream>>>(out_attn, vbuf, sums, upd);
    gemm_ln<<<dim3(6, 12), 256, 0, stream>>>(upd, wihT, gibuf, nullptr,
        352, 768, 256, nullptr, nullptr, nullptr, nullptr, b_ih, nullptr, 0);
    gemm_ln<<<dim3(6, 12), 256, 0, stream>>>(slots, whhT, ghbuf, nullptr,
        352, 768, 256, nullptr, nullptr, nullptr, nullptr, b_hh, nullptr, 0);
    gru_kernel<<<352, 256, 0, stream>>>(gibuf, ghbuf, slots, sg);
    stats_kernel<<<88, 256, 0, stream>>>(sg, meanS, rstdS, 352);
    gemm_ln<<<dim3(6, 16), 256, 0, stream>>>(sg, W1, h1buf, nullptr,
        352, 1024, 256, meanS, rstdS, gm, bm, b1, nullptr, 1);
    float* outp = (it == 2) ? out_slots : slots;
    gemm_ln<<<dim3(6, 4), 256, 0, stream>>>(h1buf, W2, outp, nullptr,
        352, 256, 1024, nullptr, nullptr, nullptr, nullptr, b2, sg, 0);
  }
}

// Round 2
// 1454.701 us; speedup vs baseline: 1.8811x; 1.8811x over previous
//
#include <hip/hip_runtime.h>

#define EPS 1e-6f
#define LN_EPS 1e-5f

typedef unsigned short u16;
typedef unsigned int u32;
typedef short bf16x8 __attribute__((ext_vector_type(8)));
typedef float f32x4 __attribute__((ext_vector_type(4)));

__device__ __forceinline__ float bf2f(u16 u) {
  return __uint_as_float(((u32)u) << 16);
}
__device__ __forceinline__ u16 f2bf(float f) {
  u32 x = __float_as_uint(f);
  x += 0x7fffu + ((x >> 16) & 1u);
  return (u16)(x >> 16);
}

// ---------------------------------------------------------------- init slots
__global__ void init_slots_kernel(const float* __restrict__ w,
                                  const float* __restrict__ z,
                                  const float* __restrict__ sigma,
                                  float* __restrict__ slots) {
  int i = blockIdx.x * 256 + threadIdx.x;  // < 90112
  int s = i & 255;
  int k = (i >> 8) % 11;
  float wv = w[k * 256 + s];
  slots[i] = wv + z[i] * sigma[0] * wv;
}

// ------------------------------------------------------- transpose W_ih/W_hh
__global__ void transpose_kernel(const float* __restrict__ wih,
                                 const float* __restrict__ whh,
                                 float* __restrict__ wihT,
                                 float* __restrict__ whhT) {
  int i = blockIdx.x * 256 + threadIdx.x;
  if (i < 196608) {
    int j = i >> 8, d = i & 255;
    wihT[d * 768 + j] = wih[i];
  } else if (i < 393216) {
    int e = i - 196608;
    int j = e >> 8, d = e & 255;
    whhT[d * 768 + j] = whh[e];
  }
}

// --------------------------------------------- build Bt[j][f] = Wkv^T (bf16)
__global__ void bt_kernel(const float* __restrict__ Wk,
                          const float* __restrict__ Wv,
                          short* __restrict__ Bt) {
  int j = blockIdx.x;   // 0..511
  int f = threadIdx.x;  // 0..255
  float val = (j < 256) ? Wk[f * 256 + j] : Wv[f * 256 + (j - 256)];
  Bt[j * 256 + f] = (short)f2bf(val);
}

// ------------------------------------------------------------- zero scratch
__global__ void zero_kernel(float* __restrict__ sums, float* __restrict__ upd) {
  int i = blockIdx.x * 256 + threadIdx.x;  // 90112
  if (i < 352) sums[i] = 0.f;
  upd[i] = 0.f;
}

// ------------------------------------------------- per-row LN stats (w=256)
__global__ void stats_kernel(const float* __restrict__ x,
                             float* __restrict__ mean, float* __restrict__ rstd,
                             int rows) {
  int wave = threadIdx.x >> 6;
  int lane = threadIdx.x & 63;
  int row = blockIdx.x * 4 + wave;
  if (row >= rows) return;
  float4 v = *(const float4*)(x + (long)row * 256 + lane * 4);
  float s = v.x + v.y + v.z + v.w;
  float s2 = v.x * v.x + v.y * v.y + v.z * v.z + v.w * v.w;
  #pragma unroll
  for (int off = 32; off > 0; off >>= 1) {
    s += __shfl_xor(s, off);
    s2 += __shfl_xor(s2, off);
  }
  if (lane == 0) {
    float mu = s * (1.0f / 256.0f);
    float var = s2 * (1.0f / 256.0f) - mu * mu;
    mean[row] = mu;
    rstd[row] = rsqrtf(var + LN_EPS);
  }
}

// --------------------------------------------------- MFMA k+v projection
// C[131072 x 512] = LN(features) @ Bt^T ; cols 0..255 -> kt[f][i] (transposed,
// bf16), cols 256..511 -> v[i][s] (normal, bf16).
// Tile 128x128, BK=64, 4 waves, mfma_f32_16x16x32_bf16.
// LDS tiles: rows of 8 16B-chunks, chunk q of row m stored at pos (q+m)&7.
__global__ __launch_bounds__(256) void gemm_kv(
    const float* __restrict__ feat, const short* __restrict__ Bt,
    const float* __restrict__ mean, const float* __restrict__ rstd,
    const float* __restrict__ gf, const float* __restrict__ bfp,
    short* __restrict__ kt, short* __restrict__ vbuf) {
  __shared__ short As[8192];  // 128 rows x 64 bf16
  __shared__ short Bs[8192];  // 128 j    x 64 bf16
  int t = threadIdx.x;
  int w = t >> 6, lane = t & 63;
  int quad = lane >> 4, l16 = lane & 15;
  int i0 = blockIdx.x * 128;
  int j0 = blockIdx.y * 128;
  int wi = (w & 1) * 64, wj = (w >> 1) * 64;
  f32x4 acc[4][4];
  #pragma unroll
  for (int a = 0; a < 4; ++a)
    #pragma unroll
    for (int b = 0; b < 4; ++b) acc[a][b] = (f32x4){0.f, 0.f, 0.f, 0.f};

  for (int ks = 0; ks < 4; ++ks) {
    // ---- stage A (fp32 load + LN + bf16 cvt), swizzled
    #pragma unroll
    for (int c = 0; c < 4; ++c) {
      int lin = t + c * 256;  // chunk 0..1023
      int m = lin >> 3, p = lin & 7;
      int q = (p - m) & 7;
      int row = i0 + m;
      int fb = ks * 64 + q * 8;
      float4 f0 = *(const float4*)(feat + (long)row * 256 + fb);
      float4 f1 = *(const float4*)(feat + (long)row * 256 + fb + 4);
      float mu = mean[row], rs = rstd[row];
      float4 g0 = *(const float4*)(gf + fb);
      float4 g1 = *(const float4*)(gf + fb + 4);
      float4 c0 = *(const float4*)(bfp + fb);
      float4 c1 = *(const float4*)(bfp + fb + 4);
      ushort4 u0, u1;
      u0.x = f2bf((f0.x - mu) * rs * g0.x + c0.x);
      u0.y = f2bf((f0.y - mu) * rs * g0.y + c0.y);
      u0.z = f2bf((f0.z - mu) * rs * g0.z + c0.z);
      u0.w = f2bf((f0.w - mu) * rs * g0.w + c0.w);
      u1.x = f2bf((f1.x - mu) * rs * g1.x + c1.x);
      u1.y = f2bf((f1.y - mu) * rs * g1.y + c1.y);
      u1.z = f2bf((f1.z - mu) * rs * g1.z + c1.z);
      u1.w = f2bf((f1.w - mu) * rs * g1.w + c1.w);
      *(ushort4*)&As[lin * 8] = u0;
      *(ushort4*)&As[lin * 8 + 4] = u1;
    }
    // ---- stage B via global_load_lds (16 B / lane)
    #pragma unroll
    for (int c = 0; c < 4; ++c) {
      int seg = w * 4 + c;        // 0..15, 1 KB each
      int lin = seg * 64 + lane;  // chunk index
      int jr = lin >> 3, p = lin & 7;
      int q = (p - jr) & 7;
      const short* gB = Bt + (long)(j0 + jr) * 256 + ks * 64 + q * 8;
      __builtin_amdgcn_global_load_lds(
          (const __attribute__((address_space(1))) void*)gB,
          (__attribute__((address_space(3))) void*)&Bs[seg * 512], 16, 0, 0);
    }
    __syncthreads();
    // ---- MFMA
    #pragma unroll
    for (int kh = 0; kh < 2; ++kh) {
      bf16x8 af[4], bfr[4];
      #pragma unroll
      for (int mi = 0; mi < 4; ++mi) {
        int m = wi + mi * 16 + l16;
        int p = ((kh * 4 + quad) + m) & 7;
        af[mi] = *(const bf16x8*)&As[m * 64 + p * 8];
      }
      #pragma unroll
      for (int ni = 0; ni < 4; ++ni) {
        int j = wj + ni * 16 + l16;
        int p = ((kh * 4 + quad) + j) & 7;
        bfr[ni] = *(const bf16x8*)&Bs[j * 64 + p * 8];
      }
      #pragma unroll
      for (int mi = 0; mi < 4; ++mi)
        #pragma unroll
        for (int ni = 0; ni < 4; ++ni)
          acc[mi][ni] = __builtin_amdgcn_mfma_f32_16x16x32_bf16(
              af[mi], bfr[ni], acc[mi][ni], 0, 0, 0);
    }
    __syncthreads();
  }
  // ---- epilogue. C/D: col=lane&15, row=quad*4+reg (in-lane = consecutive i)
  if (j0 < 256) {
    #pragma unroll
    for (int ni = 0; ni < 4; ++ni) {
      int j = j0 + wj + ni * 16 + l16;
      #pragma unroll
      for (int mi = 0; mi < 4; ++mi) {
        long ib = i0 + wi + mi * 16 + quad * 4;
        ushort4 u;
        u.x = f2bf(acc[mi][ni][0]);
        u.y = f2bf(acc[mi][ni][1]);
        u.z = f2bf(acc[mi][ni][2]);
        u.w = f2bf(acc[mi][ni][3]);
        *(ushort4*)&kt[(long)j * 131072 + ib] = u;
      }
    }
  } else {
    int colbase = j0 - 256 + wj;
    #pragma unroll
    for (int mi = 0; mi < 4; ++mi) {
      long ib = i0 + wi + mi * 16 + quad * 4;
      #pragma unroll
      for (int ni = 0; ni < 4; ++ni) {
        int col = colbase + ni * 16 + l16;
        #pragma unroll
        for (int r = 0; r < 4; ++r)
          vbuf[(ib + r) * 256 + col] = (short)f2bf(acc[mi][ni][r]);
      }
    }
  }
}

// ------------------------------------------------------------- generic GEMM
// (kept for the small 352-row GEMMs)
__global__ __launch_bounds__(256) void gemm_ln(
    const float* __restrict__ A, const float* __restrict__ W,
    float* __restrict__ Cf, u16* __restrict__ Cb,
    int M, int Nc, int Kd,
    const float* __restrict__ mean, const float* __restrict__ rstd,
    const float* __restrict__ gamma, const float* __restrict__ beta,
    const float* __restrict__ bias, const float* __restrict__ resid, int relu) {
  __shared__ float As[32][68];
  __shared__ float Bs[32][64];
  int t = threadIdx.x;
  int tx = t & 15, ty = t >> 4;
  int rowbase = blockIdx.x * 64;
  int colbase = blockIdx.y * 64;
  float acc[4][4] = {};
  int ktiles = Kd >> 5;
  for (int kt = 0; kt < ktiles; ++kt) {
    #pragma unroll
    for (int i = 0; i < 8; ++i) {
      int e = t + i * 256;
      int m = e >> 5, kk = e & 31;
      int row = rowbase + m;
      int f = kt * 32 + kk;
      float val = 0.f;
      if (row < M) {
        val = A[(long)row * Kd + f];
        if (mean) val = (val - mean[row]) * rstd[row];
        if (gamma) val = val * gamma[f] + beta[f];
      }
      As[kk][m] = val;
    }
    #pragma unroll
    for (int i = 0; i < 8; ++i) {
      int e = t + i * 256;
      int kk = e >> 6, j = e & 63;
      Bs[kk][j] = W[(long)(kt * 32 + kk) * Nc + colbase + j];
    }
    __syncthreads();
    #pragma unroll
    for (int kk = 0; kk < 32; ++kk) {
      float4 a4 = *(const float4*)&As[kk][ty * 4];
      float4 b4 = *(const float4*)&Bs[kk][tx * 4];
      float av[4] = {a4.x, a4.y, a4.z, a4.w};
      float bv[4] = {b4.x, b4.y, b4.z, b4.w};
      #pragma unroll
      for (int i = 0; i < 4; ++i)
        #pragma unroll
        for (int j = 0; j < 4; ++j) acc[i][j] += av[i] * bv[j];
    }
    __syncthreads();
  }
  #pragma unroll
  for (int i = 0; i < 4; ++i) {
    int row = rowbase + ty * 4 + i;
    if (row >= M) continue;
    int c0 = colbase + tx * 4;
    float v[4];
    #pragma unroll
    for (int j = 0; j < 4; ++j) {
      float val = acc[i][j];
      if (bias) val += bias[c0 + j];
      if (relu) val = fmaxf(val, 0.f);
      if (resid) val += resid[(long)row * Nc + c0 + j];
      v[j] = val;
    }
    if (Cb) {
      ushort4 u;
      u.x = f2bf(v[0]); u.y = f2bf(v[1]); u.z = f2bf(v[2]); u.w = f2bf(v[3]);
      *(ushort4*)&Cb[(long)row * Nc + c0] = u;
    } else {
      float4 fv = make_float4(v[0], v[1], v[2], v[3]);
      *(float4*)&Cf[(long)row * Nc + c0] = fv;
    }
  }
}

// -------------------------------------------------------- attention softmax
// kt layout [f][i], i = b*4096+n. Thread handles 2 n; softmax over kk=11
// entirely in-thread. Grid (8, 32), block 256 (512 n per block).
__global__ __launch_bounds__(256) void attn_kernel(
    const float* __restrict__ q, const short* __restrict__ kt,
    float* __restrict__ attn, float* __restrict__ sums) {
  __shared__ float qs[2816];
  int b = blockIdx.y;
  int n0 = blockIdx.x * 512;
  int t = threadIdx.x;
  for (int e = t; e < 2816; e += 256) qs[e] = q[b * 2816 + e];
  __syncthreads();
  long base = (long)b * 4096 + n0 + 2 * t;
  float a0[11], a1[11];
  #pragma unroll
  for (int kk = 0; kk < 11; ++kk) { a0[kk] = 0.f; a1[kk] = 0.f; }
  for (int f = 0; f < 256; ++f) {
    u32 u = *(const u32*)(kt + (long)f * 131072 + base);
    float k0 = bf2f((u16)(u & 0xffffu));
    float k1 = bf2f((u16)(u >> 16));
    #pragma unroll
    for (int kk = 0; kk < 11; ++kk) {
      float qv = qs[kk * 256 + f];
      a0[kk] += k0 * qv;
      a1[kk] += k1 * qv;
    }
  }
  float m0 = -1e30f, m1 = -1e30f;
  #pragma unroll
  for (int kk = 0; kk < 11; ++kk) {
    a0[kk] *= 0.0625f;  // 256^-0.5
    a1[kk] *= 0.0625f;
    m0 = fmaxf(m0, a0[kk]);
    m1 = fmaxf(m1, a1[kk]);
  }
  float s0 = 0.f, s1 = 0.f;
  #pragma unroll
  for (int kk = 0; kk < 11; ++kk) {
    a0[kk] = expf(a0[kk] - m0);
    a1[kk] = expf(a1[kk] - m1);
    s0 += a0[kk];
    s1 += a1[kk];
  }
  float i0 = 1.0f / s0, i1 = 1.0f / s1;
  #pragma unroll
  for (int kk = 0; kk < 11; ++kk) {
    float p0 = a0[kk] * i0, p1 = a1[kk] * i1;
    float2 pv = make_float2(p0, p1);
    *(float2*)(attn + ((long)b * 11 + kk) * 4096 + n0 + 2 * t) = pv;
    float s = p0 + p1;
    #pragma unroll
    for (int off = 32; off > 0; off >>= 1) s += __shfl_xor(s, off);
    if ((t & 63) == 0) atomicAdd(&sums[b * 11 + kk], s);
  }
}

// ---------------------------------------------------------------- updates
__global__ __launch_bounds__(128) void updates_kernel(
    const float* __restrict__ attn, const short* __restrict__ vb,
    const float* __restrict__ sums, float* __restrict__ upd) {
  __shared__ float as_[11 * 256];
  int b = blockIdx.y;
  int n0 = blockIdx.x * 256;
  int t = threadIdx.x;
  #pragma unroll
  for (int i = 0; i < 22; ++i) {
    int e = t + i * 128;
    int kk = e >> 8, n = e & 255;
    as_[e] = attn[((long)b * 11 + kk) * 4096 + n0 + n];
  }
  __syncthreads();
  float2 acc[11];
  #pragma unroll
  for (int kk = 0; kk < 11; ++kk) acc[kk] = make_float2(0.f, 0.f);
  const ushort2* vbase = (const ushort2*)(vb + ((long)b * 4096 + n0) * 256);
  for (int n4 = 0; n4 < 256; n4 += 4) {
    ushort2 u0 = vbase[(n4 + 0) * 128 + t];
    ushort2 u1 = vbase[(n4 + 1) * 128 + t];
    ushort2 u2 = vbase[(n4 + 2) * 128 + t];
    ushort2 u3 = vbase[(n4 + 3) * 128 + t];
    float v0x = bf2f(u0.x), v0y = bf2f(u0.y);
    float v1x = bf2f(u1.x), v1y = bf2f(u1.y);
    float v2x = bf2f(u2.x), v2y = bf2f(u2.y);
    float v3x = bf2f(u3.x), v3y = bf2f(u3.y);
    #pragma unroll
    for (int kk = 0; kk < 11; ++kk) {
      float4 a4 = *(const float4*)&as_[kk * 256 + n4];
      acc[kk].x += a4.x * v0x + a4.y * v1x + a4.z * v2x + a4.w * v3x;
      acc[kk].y += a4.x * v0y + a4.y * v1y + a4.z * v2y + a4.w * v3y;
    }
  }
  #pragma unroll
  for (int kk = 0; kk < 11; ++kk) {
    float scale = 1.0f / (sums[b * 11 + kk] + EPS);
    atomicAdd(&upd[((long)b * 11 + kk) * 256 + 2 * t], acc[kk].x * scale);
    atomicAdd(&upd[((long)b * 11 + kk) * 256 + 2 * t + 1], acc[kk].y * scale);
  }
}

// --------------------------------------------------------------- GRU gates
__global__ void gru_kernel(const float* __restrict__ gi,
                           const float* __restrict__ gh,
                           const float* __restrict__ h,
                           float* __restrict__ out) {
  int row = blockIdx.x;  // 352
  int s = threadIdx.x;   // 256
  float ir = gi[row * 768 + s];
  float iz = gi[row * 768 + 256 + s];
  float in_ = gi[row * 768 + 512 + s];
  float hr = gh[row * 768 + s];
  float hz = gh[row * 768 + 256 + s];
  float hn = gh[row * 768 + 512 + s];
  float hv = h[row * 256 + s];
  float r = 1.f / (1.f + expf(-(ir + hr)));
  float zg = 1.f / (1.f + expf(-(iz + hz)));
  float n = tanhf(in_ + r * hn);
  out[row * 256 + s] = (1.f - zg) * n + zg * hv;
}

// ---------------------------------------------------------------- launcher
extern "C" void kernel_launch(void* const* d_in, const int* in_sizes, int n_in,
                              void* d_out, int out_size, void* d_ws,
                              size_t ws_size, hipStream_t stream) {
  const float* features = (const float*)d_in[0];
  const float* sigma = (const float*)d_in[1];
  const float* z = (const float*)d_in[2];
  const float* slots_init_w = (const float*)d_in[3];
  const float* gf = (const float*)d_in[4];
  const float* bf = (const float*)d_in[5];
  const float* gs = (const float*)d_in[6];
  const float* bs = (const float*)d_in[7];
  const float* gm = (const float*)d_in[8];
  const float* bm = (const float*)d_in[9];
  const float* Wk = (const float*)d_in[10];
  const float* Wv = (const float*)d_in[11];
  const float* Wq = (const float*)d_in[12];
  const float* W_ih = (const float*)d_in[13];
  const float* W_hh = (const float*)d_in[14];
  const float* b_ih = (const float*)d_in[15];
  const float* b_hh = (const float*)d_in[16];
  const float* W1 = (const float*)d_in[17];
  const float* b1 = (const float*)d_in[18];
  const float* W2 = (const float*)d_in[19];
  const float* b2 = (const float*)d_in[20];

  float* ws = (float*)d_ws;
  size_t o = 0;
  float* meanF = ws + o; o += 131072;
  float* rstdF = ws + o; o += 131072;
  short* ktb = (short*)(ws + o); o += 16777216;  // 256 x 131072 bf16
  short* vbuf = (short*)(ws + o); o += 16777216; // 131072 x 256 bf16
  short* Bt = (short*)(ws + o); o += 65536;      // 512 x 256 bf16
  float* wihT = ws + o; o += 196608;
  float* whhT = ws + o; o += 196608;
  float* slots = ws + o; o += 90112;
  float* sg = ws + o; o += 90112;
  float* qbuf = ws + o; o += 90112;
  float* gibuf = ws + o; o += 270336;
  float* ghbuf = ws + o; o += 270336;
  float* h1buf = ws + o; o += 360448;
  float* upd = ws + o; o += 90112;
  float* sums = ws + o; o += 352;
  float* meanS = ws + o; o += 352;
  float* rstdS = ws + o; o += 352;

  float* out_slots = (float*)d_out;
  float* out_attn = (float*)d_out + 90112;

  init_slots_kernel<<<352, 256, 0, stream>>>(slots_init_w, z, sigma, slots);
  transpose_kernel<<<1536, 256, 0, stream>>>(W_ih, W_hh, wihT, whhT);
  bt_kernel<<<512, 256, 0, stream>>>(Wk, Wv, Bt);
  stats_kernel<<<32768, 256, 0, stream>>>(features, meanF, rstdF, 131072);
  gemm_kv<<<dim3(1024, 4), 256, 0, stream>>>(features, Bt, meanF, rstdF,
                                             gf, bf, ktb, vbuf);

  for (int it = 0; it < 3; ++it) {
    stats_kernel<<<88, 256, 0, stream>>>(slots, meanS, rstdS, 352);
    gemm_ln<<<dim3(6, 4), 256, 0, stream>>>(slots, Wq, qbuf, nullptr,
        352, 256, 256, meanS, rstdS, gs, bs, nullptr, nullptr, 0);
    zero_kernel<<<352, 256, 0, stream>>>(sums, upd);
    attn_kernel<<<dim3(8, 32), 256, 0, stream>>>(qbuf, ktb, out_attn, sums);
    updates_kernel<<<dim3(16, 32), 128, 0, stream>>>(out_attn, vbuf, sums, upd);
    gemm_ln<<<dim3(6, 12), 256, 0, stream>>>(upd, wihT, gibuf, nullptr,
        352, 768, 256, nullptr, nullptr, nullptr, nullptr, b_ih, nullptr, 0);
    gemm_ln<<<dim3(6, 12), 256, 0, stream>>>(slots, whhT, ghbuf, nullptr,
        352, 768, 256, nullptr, nullptr, nullptr, nullptr, b_hh, nullptr, 0);
    gru_kernel<<<352, 256, 0, stream>>>(gibuf, ghbuf, slots, sg);
    stats_kernel<<<88, 256, 0, stream>>>(sg, meanS, rstdS, 352);
    gemm_ln<<<dim3(6, 16), 256, 0, stream>>>(sg, W1, h1buf, nullptr,
        352, 1024, 256, meanS, rstdS, gm, bm, b1, nullptr, 1);
    float* outp = (it == 2) ? out_slots : slots;
    gemm_ln<<<dim3(6, 4), 256, 0, stream>>>(h1buf, W2, outp, nullptr,
        352, 256, 1024, nullptr, nullptr, nullptr, nullptr, b2, sg, 0);
  }
}

// Round 3
// 1000.583 us; speedup vs baseline: 2.7348x; 1.4539x over previous
//
#include <hip/hip_runtime.h>

#define EPS 1e-6f
#define LN_EPS 1e-5f

typedef unsigned short u16;
typedef unsigned int u32;
typedef short bf16x8 __attribute__((ext_vector_type(8)));
typedef float f32x4 __attribute__((ext_vector_type(4)));

__device__ __forceinline__ float bf2f(u16 u) {
  return __uint_as_float(((u32)u) << 16);
}
__device__ __forceinline__ u16 f2bf(float f) {
  u32 x = __float_as_uint(f);
  x += 0x7fffu + ((x >> 16) & 1u);
  return (u16)(x >> 16);
}

// ---------------------------------------------------------------- init slots
__global__ void init_slots_kernel(const float* __restrict__ w,
                                  const float* __restrict__ z,
                                  const float* __restrict__ sigma,
                                  float* __restrict__ slots) {
  int i = blockIdx.x * 256 + threadIdx.x;  // < 90112
  int s = i & 255;
  int k = (i >> 8) % 11;
  float wv = w[k * 256 + s];
  slots[i] = wv + z[i] * sigma[0] * wv;
}

// -------------------------------------------------- weight prep (one kernel)
// wihT/whhT: fp32 transposed [256][768]; W1b/W2b/Wqb: bf16 as-is; Btb: bf16
// [512 j][256 f] = [Wk|Wv]^T.
__global__ void wprep_kernel(const float* __restrict__ W_ih,
                             const float* __restrict__ W_hh,
                             const float* __restrict__ W1,
                             const float* __restrict__ W2,
                             const float* __restrict__ Wq,
                             const float* __restrict__ Wk,
                             const float* __restrict__ Wv,
                             float* __restrict__ wihT, float* __restrict__ whhT,
                             short* __restrict__ W1b, short* __restrict__ W2b,
                             short* __restrict__ Wqb, short* __restrict__ Btb) {
  int e = blockIdx.x * 256 + threadIdx.x;
  if (e < 196608) {
    int j = e >> 8, d = e & 255;
    wihT[d * 768 + j] = W_ih[e];
  } else if (e < 393216) {
    int e2 = e - 196608;
    int j = e2 >> 8, d = e2 & 255;
    whhT[d * 768 + j] = W_hh[e2];
  } else if (e < 655360) {
    int e2 = e - 393216;
    W1b[e2] = (short)f2bf(W1[e2]);
  } else if (e < 917504) {
    int e2 = e - 655360;
    W2b[e2] = (short)f2bf(W2[e2]);
  } else if (e < 983040) {
    int e2 = e - 917504;
    Wqb[e2] = (short)f2bf(Wq[e2]);
  } else if (e < 1114112) {
    int e2 = e - 983040;
    int f = e2 >> 9, j = e2 & 511;
    float v = (j < 256) ? Wk[f * 256 + j] : Wv[f * 256 + (j - 256)];
    Btb[j * 256 + f] = (short)f2bf(v);
  }
}

// ------------------------------------------------------------- zero scratch
__global__ void zero_kernel(float* __restrict__ sums, float* __restrict__ upd) {
  int i = blockIdx.x * 256 + threadIdx.x;  // 90112
  if (i < 352) sums[i] = 0.f;
  upd[i] = 0.f;
}

// --------------------------------------------------- MFMA k+v projection
// C[131072 x 512] = LN(features) @ Btb^T. Full-K A tile (fused LN) staged
// once; 4 j-quarters x 4 k-steps with 16KB B tiles. j<256 -> kt[f][i]
// (transposed store, normal mfma); j>=256 -> v[i][s] (swapped-operand mfma
// so stores are packed ushort4).
__global__ __launch_bounds__(256) void gemm_kv(
    const float* __restrict__ feat, const short* __restrict__ Btb,
    const float* __restrict__ gf, const float* __restrict__ bfp,
    short* __restrict__ kt, short* __restrict__ vbuf) {
  __shared__ short As[32768];  // 128 rows x 256 k, 16B chunks rotated by row
  __shared__ short Bs[8192];   // 128 j x 64 k, chunks rotated by j
  int t = threadIdx.x;
  int w = t >> 6, lane = t & 63;
  int quad = lane >> 4, l16 = lane & 15;
  int i0 = blockIdx.x * 128;
  int wi = (w & 1) * 64, wj = (w >> 1) * 64;

  // ---- stage A: fused LN stats + bf16 cvt, 2 passes of 64 rows
  {
    int rq = t >> 2;  // 0..63
    int qd = t & 3;   // quarter of the row
    for (int pass = 0; pass < 2; ++pass) {
      int r = pass * 64 + rq;
      const float* frow = feat + (long)(i0 + r) * 256 + qd * 64;
      float4 fv[16];
      float s = 0.f, s2 = 0.f;
      #pragma unroll
      for (int i = 0; i < 16; ++i) {
        fv[i] = *(const float4*)(frow + i * 4);
        s += fv[i].x + fv[i].y + fv[i].z + fv[i].w;
        s2 += fv[i].x * fv[i].x + fv[i].y * fv[i].y + fv[i].z * fv[i].z +
              fv[i].w * fv[i].w;
      }
      s += __shfl_xor(s, 1); s2 += __shfl_xor(s2, 1);
      s += __shfl_xor(s, 2); s2 += __shfl_xor(s2, 2);
      float mu = s * (1.f / 256.f);
      float rs = rsqrtf(s2 * (1.f / 256.f) - mu * mu + LN_EPS);
      #pragma unroll
      for (int c = 0; c < 8; ++c) {  // 8 chunks of 8 elems
        float4 a = fv[c * 2], b = fv[c * 2 + 1];
        int fb = qd * 64 + c * 8;
        float4 g0 = *(const float4*)(gf + fb);
        float4 g1 = *(const float4*)(gf + fb + 4);
        float4 e0 = *(const float4*)(bfp + fb);
        float4 e1 = *(const float4*)(bfp + fb + 4);
        ushort4 u0, u1;
        u0.x = f2bf((a.x - mu) * rs * g0.x + e0.x);
        u0.y = f2bf((a.y - mu) * rs * g0.y + e0.y);
        u0.z = f2bf((a.z - mu) * rs * g0.z + e0.z);
        u0.w = f2bf((a.w - mu) * rs * g0.w + e0.w);
        u1.x = f2bf((b.x - mu) * rs * g1.x + e1.x);
        u1.y = f2bf((b.y - mu) * rs * g1.y + e1.y);
        u1.z = f2bf((b.z - mu) * rs * g1.z + e1.z);
        u1.w = f2bf((b.w - mu) * rs * g1.w + e1.w);
        int q = qd * 8 + c;          // chunk index 0..31 within row
        int p = (q + r) & 31;        // rotate by row
        *(ushort4*)&As[r * 256 + p * 8] = u0;
        *(ushort4*)&As[r * 256 + p * 8 + 4] = u1;
      }
    }
  }

  f32x4 acc[4][4];
  for (int jq = 0; jq < 4; ++jq) {
    #pragma unroll
    for (int a = 0; a < 4; ++a)
      #pragma unroll
      for (int b = 0; b < 4; ++b) acc[a][b] = (f32x4){0.f, 0.f, 0.f, 0.f};
    bool vside = jq >= 2;
    for (int ks = 0; ks < 4; ++ks) {
      __syncthreads();  // prior mfma done reading Bs (and A writes flushed)
      #pragma unroll
      for (int c = 0; c < 4; ++c) {
        int lin = c * 256 + t;  // chunk 0..1023
        int jr = lin >> 3, p = lin & 7;
        int q = (p - jr) & 7;
        const short* gB = Btb + (long)(jq * 128 + jr) * 256 + ks * 64 + q * 8;
        __builtin_amdgcn_global_load_lds(
            (const __attribute__((address_space(1))) void*)gB,
            (__attribute__((address_space(3))) void*)&Bs[lin * 8], 16, 0, 0);
      }
      __syncthreads();
      #pragma unroll
      for (int kh = 0; kh < 2; ++kh) {
        bf16x8 af[4], bfr[4];
        #pragma unroll
        for (int mi = 0; mi < 4; ++mi) {
          int m = wi + mi * 16 + l16;
          int qk = ks * 8 + kh * 4 + quad;
          int p = (qk + m) & 31;
          af[mi] = *(const bf16x8*)&As[m * 256 + p * 8];
        }
        #pragma unroll
        for (int ni = 0; ni < 4; ++ni) {
          int j = wj + ni * 16 + l16;
          int qb = kh * 4 + quad;
          int p = (qb + j) & 7;
          bfr[ni] = *(const bf16x8*)&Bs[j * 64 + p * 8];
        }
        if (!vside) {
          #pragma unroll
          for (int mi = 0; mi < 4; ++mi)
            #pragma unroll
            for (int ni = 0; ni < 4; ++ni)
              acc[mi][ni] = __builtin_amdgcn_mfma_f32_16x16x32_bf16(
                  af[mi], bfr[ni], acc[mi][ni], 0, 0, 0);
        } else {
          #pragma unroll
          for (int mi = 0; mi < 4; ++mi)
            #pragma unroll
            for (int ni = 0; ni < 4; ++ni)
              acc[mi][ni] = __builtin_amdgcn_mfma_f32_16x16x32_bf16(
                  bfr[ni], af[mi], acc[mi][ni], 0, 0, 0);
        }
      }
    }
    // ---- epilogue for this j-quarter
    if (!vside) {
      // D: col(lane&15)=j, row(quad*4+reg)=i  -> kt[j][i], 8B packed in i
      #pragma unroll
      for (int ni = 0; ni < 4; ++ni) {
        int j = jq * 128 + wj + ni * 16 + l16;
        #pragma unroll
        for (int mi = 0; mi < 4; ++mi) {
          long ib = i0 + wi + mi * 16 + quad * 4;
          ushort4 u;
          u.x = f2bf(acc[mi][ni][0]);
          u.y = f2bf(acc[mi][ni][1]);
          u.z = f2bf(acc[mi][ni][2]);
          u.w = f2bf(acc[mi][ni][3]);
          *(ushort4*)&kt[(long)j * 131072 + ib] = u;
        }
      }
    } else {
      // swapped: col(lane&15)=i, row(quad*4+reg)=s -> v[i][s], 8B packed in s
      #pragma unroll
      for (int mi = 0; mi < 4; ++mi) {
        long i = i0 + wi + mi * 16 + l16;
        #pragma unroll
        for (int ni = 0; ni < 4; ++ni) {
          int sb = (jq - 2) * 128 + wj + ni * 16 + quad * 4;
          ushort4 u;
          u.x = f2bf(acc[mi][ni][0]);
          u.y = f2bf(acc[mi][ni][1]);
          u.z = f2bf(acc[mi][ni][2]);
          u.w = f2bf(acc[mi][ni][3]);
          *(ushort4*)&vbuf[i * 256 + sb] = u;
        }
      }
    }
  }
}

// ----------------------------------------------------- q projection (iter 0)
__global__ __launch_bounds__(256) void qproj_kernel(
    const float* __restrict__ slots, const float* __restrict__ gs,
    const float* __restrict__ bs, const short* __restrict__ Wqb,
    float* __restrict__ qout) {
  __shared__ float lnq[256];
  __shared__ float red[8];
  int row = blockIdx.x, t = threadIdx.x;
  int w = t >> 6, lane = t & 63;
  float x = slots[(long)row * 256 + t];
  float s = x, s2 = x * x;
  #pragma unroll
  for (int off = 32; off > 0; off >>= 1) {
    s += __shfl_xor(s, off);
    s2 += __shfl_xor(s2, off);
  }
  if (lane == 0) { red[w * 2] = s; red[w * 2 + 1] = s2; }
  __syncthreads();
  float st = red[0] + red[2] + red[4] + red[6];
  float st2 = red[1] + red[3] + red[5] + red[7];
  float mu = st * (1.f / 256.f);
  float rs = rsqrtf(st2 * (1.f / 256.f) - mu * mu + LN_EPS);
  lnq[t] = (x - mu) * rs * gs[t] + bs[t];
  __syncthreads();
  float acc = 0.f;
  for (int k = 0; k < 256; ++k)
    acc += lnq[k] * bf2f((u16)Wqb[k * 256 + t]);
  qout[(long)row * 256 + t] = acc;
}

// -------------------------------------------------------- attention softmax
// kt layout [f][i], i = b*4096+n. Thread handles 2 n; softmax over kk=11
// in-thread. q staged transposed [f][12] -> 3x b128 broadcast per f.
__global__ __launch_bounds__(256) void attn_kernel(
    const float* __restrict__ q, const short* __restrict__ kt,
    float* __restrict__ attn, float* __restrict__ sums) {
  __shared__ float qs[3072];  // [f][12]
  int b = blockIdx.y;
  int n0 = blockIdx.x * 512;
  int t = threadIdx.x;
  for (int e = t; e < 2816; e += 256) {
    int kk = e >> 8, f = e & 255;
    qs[f * 12 + kk] = q[b * 2816 + e];
  }
  __syncthreads();
  long base = (long)b * 4096 + n0 + 2 * t;
  float a0[11], a1[11];
  #pragma unroll
  for (int kk = 0; kk < 11; ++kk) { a0[kk] = 0.f; a1[kk] = 0.f; }
  for (int f = 0; f < 256; ++f) {
    u32 u = *(const u32*)(kt + (long)f * 131072 + base);
    float k0 = bf2f((u16)(u & 0xffffu));
    float k1 = bf2f((u16)(u >> 16));
    float4 qa = *(const float4*)&qs[f * 12];
    float4 qb = *(const float4*)&qs[f * 12 + 4];
    float4 qc = *(const float4*)&qs[f * 12 + 8];
    a0[0] += k0 * qa.x; a1[0] += k1 * qa.x;
    a0[1] += k0 * qa.y; a1[1] += k1 * qa.y;
    a0[2] += k0 * qa.z; a1[2] += k1 * qa.z;
    a0[3] += k0 * qa.w; a1[3] += k1 * qa.w;
    a0[4] += k0 * qb.x; a1[4] += k1 * qb.x;
    a0[5] += k0 * qb.y; a1[5] += k1 * qb.y;
    a0[6] += k0 * qb.z; a1[6] += k1 * qb.z;
    a0[7] += k0 * qb.w; a1[7] += k1 * qb.w;
    a0[8] += k0 * qc.x; a1[8] += k1 * qc.x;
    a0[9] += k0 * qc.y; a1[9] += k1 * qc.y;
    a0[10] += k0 * qc.z; a1[10] += k1 * qc.z;
  }
  float m0 = -1e30f, m1 = -1e30f;
  #pragma unroll
  for (int kk = 0; kk < 11; ++kk) {
    a0[kk] *= 0.0625f;  // 256^-0.5
    a1[kk] *= 0.0625f;
    m0 = fmaxf(m0, a0[kk]);
    m1 = fmaxf(m1, a1[kk]);
  }
  float s0 = 0.f, s1 = 0.f;
  #pragma unroll
  for (int kk = 0; kk < 11; ++kk) {
    a0[kk] = expf(a0[kk] - m0);
    a1[kk] = expf(a1[kk] - m1);
    s0 += a0[kk];
    s1 += a1[kk];
  }
  float i0 = 1.0f / s0, i1 = 1.0f / s1;
  #pragma unroll
  for (int kk = 0; kk < 11; ++kk) {
    float p0 = a0[kk] * i0, p1 = a1[kk] * i1;
    float2 pv = make_float2(p0, p1);
    *(float2*)(attn + ((long)b * 11 + kk) * 4096 + n0 + 2 * t) = pv;
    float s = p0 + p1;
    #pragma unroll
    for (int off = 32; off > 0; off >>= 1) s += __shfl_xor(s, off);
    if ((t & 63) == 0) atomicAdd(&sums[b * 11 + kk], s);
  }
}

// ---------------------------------------------------------------- updates
__global__ __launch_bounds__(128) void updates_kernel(
    const float* __restrict__ attn, const short* __restrict__ vb,
    const float* __restrict__ sums, float* __restrict__ upd) {
  __shared__ float as_[11 * 256];
  int b = blockIdx.y;
  int n0 = blockIdx.x * 256;
  int t = threadIdx.x;
  #pragma unroll
  for (int i = 0; i < 22; ++i) {
    int e = t + i * 128;
    int kk = e >> 8, n = e & 255;
    as_[e] = attn[((long)b * 11 + kk) * 4096 + n0 + n];
  }
  __syncthreads();
  float2 acc[11];
  #pragma unroll
  for (int kk = 0; kk < 11; ++kk) acc[kk] = make_float2(0.f, 0.f);
  const ushort2* vbase = (const ushort2*)(vb + ((long)b * 4096 + n0) * 256);
  for (int n4 = 0; n4 < 256; n4 += 4) {
    ushort2 u0 = vbase[(n4 + 0) * 128 + t];
    ushort2 u1 = vbase[(n4 + 1) * 128 + t];
    ushort2 u2 = vbase[(n4 + 2) * 128 + t];
    ushort2 u3 = vbase[(n4 + 3) * 128 + t];
    float v0x = bf2f(u0.x), v0y = bf2f(u0.y);
    float v1x = bf2f(u1.x), v1y = bf2f(u1.y);
    float v2x = bf2f(u2.x), v2y = bf2f(u2.y);
    float v3x = bf2f(u3.x), v3y = bf2f(u3.y);
    #pragma unroll
    for (int kk = 0; kk < 11; ++kk) {
      float4 a4 = *(const float4*)&as_[kk * 256 + n4];
      acc[kk].x += a4.x * v0x + a4.y * v1x + a4.z * v2x + a4.w * v3x;
      acc[kk].y += a4.x * v0y + a4.y * v1y + a4.z * v2y + a4.w * v3y;
    }
  }
  #pragma unroll
  for (int kk = 0; kk < 11; ++kk) {
    float scale = 1.0f / (sums[b * 11 + kk] + EPS);
    atomicAdd(&upd[((long)b * 11 + kk) * 256 + 2 * t], acc[kk].x * scale);
    atomicAdd(&upd[((long)b * 11 + kk) * 256 + 2 * t + 1], acc[kk].y * scale);
  }
}

// -------------------------------------------- fused slot step (4 rows/block)
// slots' = GRU(upd, slots); slots_out = slots' + MLP(LN(slots')); optionally
// emits q = LN(slots_out)@Wq for the next iteration.
__global__ __launch_bounds__(256) void slot_step(
    const float* __restrict__ upd, const float* __restrict__ slots_in,
    const float* __restrict__ wihT, const float* __restrict__ whhT,
    const float* __restrict__ b_ih, const float* __restrict__ b_hh,
    const float* __restrict__ gm, const float* __restrict__ bm,
    const short* __restrict__ W1b, const float* __restrict__ b1,
    const short* __restrict__ W2b, const float* __restrict__ b2,
    const float* __restrict__ gs, const float* __restrict__ bs,
    const short* __restrict__ Wqb,
    float* __restrict__ slots_out, float* __restrict__ qout, int emit_q) {
  __shared__ float xs[4][256], hs[4][256], sgv[4][256], ln1[4][256];
  __shared__ float giv[4][768], ghv[4][768];
  __shared__ float h1v[4][1024];
  __shared__ float red[4][2];
  int t = threadIdx.x;
  int w = t >> 6, lane = t & 63;
  int r0 = blockIdx.x * 4;
  {
    float4 xv = *(const float4*)(upd + (long)(r0 + w) * 256 + lane * 4);
    *(float4*)&xs[w][lane * 4] = xv;
    float4 hv = *(const float4*)(slots_in + (long)(r0 + w) * 256 + lane * 4);
    *(float4*)&hs[w][lane * 4] = hv;
  }
  __syncthreads();
  // ---- gi = x@W_ihT + b_ih ; gh = h@W_hhT + b_hh  (192 threads x 4 cols)
  if (t < 192) {
    float accI[4][4] = {}, accH[4][4] = {};
    for (int k = 0; k < 256; ++k) {
      float4 wi4 = *(const float4*)(wihT + k * 768 + 4 * t);
      float4 wh4 = *(const float4*)(whhT + k * 768 + 4 * t);
      float wI[4] = {wi4.x, wi4.y, wi4.z, wi4.w};
      float wH[4] = {wh4.x, wh4.y, wh4.z, wh4.w};
      float xr[4] = {xs[0][k], xs[1][k], xs[2][k], xs[3][k]};
      float hr[4] = {hs[0][k], hs[1][k], hs[2][k], hs[3][k]};
      #pragma unroll
      for (int row = 0; row < 4; ++row)
        #pragma unroll
        for (int j = 0; j < 4; ++j) {
          accI[row][j] += xr[row] * wI[j];
          accH[row][j] += hr[row] * wH[j];
        }
    }
    #pragma unroll
    for (int row = 0; row < 4; ++row)
      #pragma unroll
      for (int j = 0; j < 4; ++j) {
        giv[row][4 * t + j] = accI[row][j] + b_ih[4 * t + j];
        ghv[row][4 * t + j] = accH[row][j] + b_hh[4 * t + j];
      }
  }
  __syncthreads();
  // ---- GRU gates (thread = s, loop rows)
  #pragma unroll
  for (int row = 0; row < 4; ++row) {
    float irv = giv[row][t], izv = giv[row][256 + t], inv = giv[row][512 + t];
    float hrv = ghv[row][t], hzv = ghv[row][256 + t], hnv = ghv[row][512 + t];
    float hv = hs[row][t];
    float rg = 1.f / (1.f + expf(-(irv + hrv)));
    float zg = 1.f / (1.f + expf(-(izv + hzv)));
    float ng = tanhf(inv + rg * hnv);
    sgv[row][t] = (1.f - zg) * ng + zg * hv;
  }
  __syncthreads();
  // ---- LN stats (wave w -> row w)
  {
    float4 sv = *(const float4*)&sgv[w][lane * 4];
    float s = sv.x + sv.y + sv.z + sv.w;
    float s2 = sv.x * sv.x + sv.y * sv.y + sv.z * sv.z + sv.w * sv.w;
    #pragma unroll
    for (int off = 32; off > 0; off >>= 1) {
      s += __shfl_xor(s, off);
      s2 += __shfl_xor(s2, off);
    }
    if (lane == 0) {
      float mu = s * (1.f / 256.f);
      red[w][0] = mu;
      red[w][1] = rsqrtf(s2 * (1.f / 256.f) - mu * mu + LN_EPS);
    }
  }
  __syncthreads();
  #pragma unroll
  for (int row = 0; row < 4; ++row)
    ln1[row][t] = (sgv[row][t] - red[row][0]) * red[row][1] * gm[t] + bm[t];
  __syncthreads();
  // ---- W1 + relu (thread x 4 cols of 1024)
  {
    float acc1[4][4] = {};
    for (int k = 0; k < 256; ++k) {
      ushort4 w4 = *(const ushort4*)(W1b + k * 1024 + 4 * t);
      float wv[4] = {bf2f(w4.x), bf2f(w4.y), bf2f(w4.z), bf2f(w4.w)};
      float lr[4] = {ln1[0][k], ln1[1][k], ln1[2][k], ln1[3][k]};
      #pragma unroll
      for (int row = 0; row < 4; ++row)
        #pragma unroll
        for (int j = 0; j < 4; ++j) acc1[row][j] += lr[row] * wv[j];
    }
    #pragma unroll
    for (int row = 0; row < 4; ++row)
      #pragma unroll
      for (int j = 0; j < 4; ++j)
        h1v[row][4 * t + j] = fmaxf(acc1[row][j] + b1[4 * t + j], 0.f);
  }
  __syncthreads();
  // ---- W2 + bias + resid
  float outv[4];
  {
    float acc2[4] = {};
    for (int k = 0; k < 1024; ++k) {
      float wv = bf2f((u16)W2b[k * 256 + t]);
      #pragma unroll
      for (int row = 0; row < 4; ++row) acc2[row] += h1v[row][k] * wv;
    }
    float bb = b2[t];
    #pragma unroll
    for (int row = 0; row < 4; ++row) {
      outv[row] = acc2[row] + bb + sgv[row][t];
      slots_out[(long)(r0 + row) * 256 + t] = outv[row];
    }
  }
  // ---- q for next iteration
  if (emit_q) {
    __syncthreads();
    #pragma unroll
    for (int row = 0; row < 4; ++row) xs[row][t] = outv[row];
    __syncthreads();
    {
      float4 sv = *(const float4*)&xs[w][lane * 4];
      float s = sv.x + sv.y + sv.z + sv.w;
      float s2 = sv.x * sv.x + sv.y * sv.y + sv.z * sv.z + sv.w * sv.w;
      #pragma unroll
      for (int off = 32; off > 0; off >>= 1) {
        s += __shfl_xor(s, off);
        s2 += __shfl_xor(s2, off);
      }
      if (lane == 0) {
        float mu = s * (1.f / 256.f);
        red[w][0] = mu;
        red[w][1] = rsqrtf(s2 * (1.f / 256.f) - mu * mu + LN_EPS);
      }
    }
    __syncthreads();
    #pragma unroll
    for (int row = 0; row < 4; ++row)
      hs[row][t] = (xs[row][t] - red[row][0]) * red[row][1] * gs[t] + bs[t];
    __syncthreads();
    float accq[4] = {};
    for (int k = 0; k < 256; ++k) {
      float wv = bf2f((u16)Wqb[k * 256 + t]);
      #pragma unroll
      for (int row = 0; row < 4; ++row) accq[row] += hs[row][k] * wv;
    }
    #pragma unroll
    for (int row = 0; row < 4; ++row)
      qout[(long)(r0 + row) * 256 + t] = accq[row];
  }
}

// ---------------------------------------------------------------- launcher
extern "C" void kernel_launch(void* const* d_in, const int* in_sizes, int n_in,
                              void* d_out, int out_size, void* d_ws,
                              size_t ws_size, hipStream_t stream) {
  const float* features = (const float*)d_in[0];
  const float* sigma = (const float*)d_in[1];
  const float* z = (const float*)d_in[2];
  const float* slots_init_w = (const float*)d_in[3];
  const float* gf = (const float*)d_in[4];
  const float* bf = (const float*)d_in[5];
  const float* gs = (const float*)d_in[6];
  const float* bs = (const float*)d_in[7];
  const float* gm = (const float*)d_in[8];
  const float* bm = (const float*)d_in[9];
  const float* Wk = (const float*)d_in[10];
  const float* Wv = (const float*)d_in[11];
  const float* Wq = (const float*)d_in[12];
  const float* W_ih = (const float*)d_in[13];
  const float* W_hh = (const float*)d_in[14];
  const float* b_ih = (const float*)d_in[15];
  const float* b_hh = (const float*)d_in[16];
  const float* W1 = (const float*)d_in[17];
  const float* b1 = (const float*)d_in[18];
  const float* W2 = (const float*)d_in[19];
  const float* b2 = (const float*)d_in[20];

  float* ws = (float*)d_ws;
  size_t o = 0;
  short* ktb = (short*)(ws + o); o += 16777216;   // 256 x 131072 bf16
  short* vbuf = (short*)(ws + o); o += 16777216;  // 131072 x 256 bf16
  short* Btb = (short*)(ws + o); o += 65536;      // 512 x 256 bf16
  float* wihT = ws + o; o += 196608;              // fp32 [256][768]
  float* whhT = ws + o; o += 196608;
  short* W1b = (short*)(ws + o); o += 131072;     // 256x1024 bf16
  short* W2b = (short*)(ws + o); o += 131072;     // 1024x256 bf16
  short* Wqb = (short*)(ws + o); o += 32768;      // 256x256 bf16
  float* slots = ws + o; o += 90112;
  float* qbuf = ws + o; o += 90112;
  float* upd = ws + o; o += 90112;
  float* sums = ws + o; o += 352;

  float* out_slots = (float*)d_out;
  float* out_attn = (float*)d_out + 90112;

  init_slots_kernel<<<352, 256, 0, stream>>>(slots_init_w, z, sigma, slots);
  wprep_kernel<<<4352, 256, 0, stream>>>(W_ih, W_hh, W1, W2, Wq, Wk, Wv,
                                         wihT, whhT, W1b, W2b, Wqb, Btb);
  gemm_kv<<<1024, 256, 0, stream>>>(features, Btb, gf, bf, ktb, vbuf);
  qproj_kernel<<<352, 256, 0, stream>>>(slots, gs, bs, Wqb, qbuf);

  for (int it = 0; it < 3; ++it) {
    zero_kernel<<<352, 256, 0, stream>>>(sums, upd);
    attn_kernel<<<dim3(8, 32), 256, 0, stream>>>(qbuf, ktb, out_attn, sums);
    updates_kernel<<<dim3(16, 32), 128, 0, stream>>>(out_attn, vbuf, sums, upd);
    slot_step<<<88, 256, 0, stream>>>(
        upd, slots, wihT, whhT, b_ih, b_hh, gm, bm, W1b, b1, W2b, b2,
        gs, bs, Wqb, (it == 2) ? out_slots : slots, qbuf, (it < 2) ? 1 : 0);
  }
}

// Round 5
// 775.407 us; speedup vs baseline: 3.5290x; 1.2904x over previous
//
#include <hip/hip_runtime.h>

#define EPS 1e-6f
#define LN_EPS 1e-5f

typedef unsigned short u16;
typedef unsigned int u32;
typedef short bf16x8 __attribute__((ext_vector_type(8)));
typedef float f32x4 __attribute__((ext_vector_type(4)));

__device__ __forceinline__ float bf2f(u16 u) {
  return __uint_as_float(((u32)u) << 16);
}
__device__ __forceinline__ u16 f2bf(float f) {
  u32 x = __float_as_uint(f);
  x += 0x7fffu + ((x >> 16) & 1u);
  return (u16)(x >> 16);
}

// ------------------------------------------- init slots + zero upd/sums
__global__ void init_slots_kernel(const float* __restrict__ w,
                                  const float* __restrict__ z,
                                  const float* __restrict__ sigma,
                                  float* __restrict__ slots,
                                  float* __restrict__ upd,
                                  float* __restrict__ sums) {
  int i = blockIdx.x * 256 + threadIdx.x;  // < 90112
  int s = i & 255;
  int k = (i >> 8) % 11;
  float wv = w[k * 256 + s];
  slots[i] = wv + z[i] * sigma[0] * wv;
  upd[i] = 0.f;
  if (i < 352) sums[i] = 0.f;
}

// -------------------------------------------------- weight prep (one kernel)
__global__ void wprep_kernel(const float* __restrict__ W_ih,
                             const float* __restrict__ W_hh,
                             const float* __restrict__ W1,
                             const float* __restrict__ W2,
                             const float* __restrict__ Wq,
                             const float* __restrict__ Wk,
                             const float* __restrict__ Wv,
                             float* __restrict__ wihT, float* __restrict__ whhT,
                             short* __restrict__ W1b, short* __restrict__ W2b,
                             short* __restrict__ Wqb, short* __restrict__ Btb) {
  int e = blockIdx.x * 256 + threadIdx.x;
  if (e < 196608) {
    int j = e >> 8, d = e & 255;
    wihT[d * 768 + j] = W_ih[e];
  } else if (e < 393216) {
    int e2 = e - 196608;
    int j = e2 >> 8, d = e2 & 255;
    whhT[d * 768 + j] = W_hh[e2];
  } else if (e < 655360) {
    int e2 = e - 393216;
    W1b[e2] = (short)f2bf(W1[e2]);
  } else if (e < 917504) {
    int e2 = e - 655360;
    W2b[e2] = (short)f2bf(W2[e2]);
  } else if (e < 983040) {
    int e2 = e - 917504;
    Wqb[e2] = (short)f2bf(Wq[e2]);
  } else if (e < 1114112) {
    int e2 = e - 983040;
    int f = e2 >> 9, j = e2 & 511;
    float v = (j < 256) ? Wk[f * 256 + j] : Wv[f * 256 + (j - 256)];
    Btb[j * 256 + f] = (short)f2bf(v);
  }
}

// --------------------------------------------------- MFMA k+v projection
// C[131072 x 512] = LN(features) @ Btb^T. 64-row blocks (grid 2048); full-K
// A tile (fused LN -> bf16) staged once; 16 (jq,ks) steps with double-buffered
// 16KB B tiles prefetched via global_load_lds before each MFMA phase.
// A swizzle (injective + bank-balanced): chunk q (8 bf16) of row r stored at
//   p = (q & 24) | ((q + 2*(q>>3) + r) & 7)
// store groups = (c + 2*qd + r)&7 -> 2/quarter-wave; read groups = const+m.
__global__ __launch_bounds__(256) void gemm_kv(
    const float* __restrict__ feat, const short* __restrict__ Btb,
    const float* __restrict__ gf, const float* __restrict__ bfp,
    short* __restrict__ kt, short* __restrict__ vbuf) {
  __shared__ short As[16384];    // 64 rows x 256 k
  __shared__ short Bs[2][8192];  // 2 x (128 j x 64 k)
  int t = threadIdx.x;
  int w = t >> 6, lane = t & 63;
  int quad = lane >> 4, l16 = lane & 15;
  int i0 = blockIdx.x * 64;
  int wi = (w & 1) * 32, wj = (w >> 1) * 64;

  // ---- prefetch B(jq=0, ks=0) into buf 0
  {
    #pragma unroll
    for (int c = 0; c < 4; ++c) {
      int lin = c * 256 + t;
      int jr = lin >> 3, p = lin & 7;
      int q = (p - jr) & 7;
      const short* gB = Btb + (long)jr * 256 + q * 8;
      __builtin_amdgcn_global_load_lds(
          (const __attribute__((address_space(1))) void*)gB,
          (__attribute__((address_space(3))) void*)&Bs[0][lin * 8], 16, 0, 0);
    }
  }

  // ---- stage A: fused LN stats + bf16 cvt (thread = quarter of row)
  {
    int r = t >> 2;   // 0..63
    int qd = t & 3;   // quarter
    const float* frow = feat + (long)(i0 + r) * 256 + qd * 64;
    float4 fv[16];
    float s = 0.f, s2 = 0.f;
    #pragma unroll
    for (int i = 0; i < 16; ++i) {
      fv[i] = *(const float4*)(frow + i * 4);
      s += fv[i].x + fv[i].y + fv[i].z + fv[i].w;
      s2 += fv[i].x * fv[i].x + fv[i].y * fv[i].y + fv[i].z * fv[i].z +
            fv[i].w * fv[i].w;
    }
    s += __shfl_xor(s, 1); s2 += __shfl_xor(s2, 1);
    s += __shfl_xor(s, 2); s2 += __shfl_xor(s2, 2);
    float mu = s * (1.f / 256.f);
    float rs = rsqrtf(s2 * (1.f / 256.f) - mu * mu + LN_EPS);
    #pragma unroll
    for (int c = 0; c < 8; ++c) {
      float4 a = fv[c * 2], b = fv[c * 2 + 1];
      int fb = qd * 64 + c * 8;
      float4 g0 = *(const float4*)(gf + fb);
      float4 g1 = *(const float4*)(gf + fb + 4);
      float4 e0 = *(const float4*)(bfp + fb);
      float4 e1 = *(const float4*)(bfp + fb + 4);
      bf16x8 pk;
      pk[0] = (short)f2bf((a.x - mu) * rs * g0.x + e0.x);
      pk[1] = (short)f2bf((a.y - mu) * rs * g0.y + e0.y);
      pk[2] = (short)f2bf((a.z - mu) * rs * g0.z + e0.z);
      pk[3] = (short)f2bf((a.w - mu) * rs * g0.w + e0.w);
      pk[4] = (short)f2bf((b.x - mu) * rs * g1.x + e1.x);
      pk[5] = (short)f2bf((b.y - mu) * rs * g1.y + e1.y);
      pk[6] = (short)f2bf((b.z - mu) * rs * g1.z + e1.z);
      pk[7] = (short)f2bf((b.w - mu) * rs * g1.w + e1.w);
      // p = (q & 24) | ((q + 2*qd + r) & 7), q = qd*8 + c
      int p = qd * 8 + ((c + 2 * qd + r) & 7);
      *(bf16x8*)&As[r * 256 + p * 8] = pk;
    }
  }
  __syncthreads();

  f32x4 acc[2][4];
  #pragma unroll
  for (int a = 0; a < 2; ++a)
    #pragma unroll
    for (int b = 0; b < 4; ++b) acc[a][b] = (f32x4){0.f, 0.f, 0.f, 0.f};

  for (int idx = 0; idx < 16; ++idx) {
    int jq = idx >> 2, ks = idx & 3;
    int buf = idx & 1;
    // ---- prefetch next B tile into other buffer
    if (idx < 15) {
      int jn = (idx + 1) >> 2, kn = (idx + 1) & 3;
      #pragma unroll
      for (int c = 0; c < 4; ++c) {
        int lin = c * 256 + t;
        int jr = lin >> 3, p = lin & 7;
        int q = (p - jr) & 7;
        const short* gB = Btb + (long)(jn * 128 + jr) * 256 + kn * 64 + q * 8;
        __builtin_amdgcn_global_load_lds(
            (const __attribute__((address_space(1))) void*)gB,
            (__attribute__((address_space(3))) void*)&Bs[buf ^ 1][lin * 8],
            16, 0, 0);
      }
    }
    // ---- MFMA on current buffer
    #pragma unroll
    for (int kh = 0; kh < 2; ++kh) {
      bf16x8 af[2], bfr[4];
      #pragma unroll
      for (int mi = 0; mi < 2; ++mi) {
        int m = wi + mi * 16 + l16;
        // chunk qk = ks*8 + kh*4 + quad; p = ks*8 + ((qk + 2*ks + m)&7)
        int p = ks * 8 + ((kh * 4 + quad + 2 * ks + m) & 7);
        af[mi] = *(const bf16x8*)&As[m * 256 + p * 8];
      }
      #pragma unroll
      for (int ni = 0; ni < 4; ++ni) {
        int j = wj + ni * 16 + l16;
        int p = ((kh * 4 + quad) + j) & 7;
        bfr[ni] = *(const bf16x8*)&Bs[buf][j * 64 + p * 8];
      }
      if (jq < 2) {
        #pragma unroll
        for (int mi = 0; mi < 2; ++mi)
          #pragma unroll
          for (int ni = 0; ni < 4; ++ni)
            acc[mi][ni] = __builtin_amdgcn_mfma_f32_16x16x32_bf16(
                af[mi], bfr[ni], acc[mi][ni], 0, 0, 0);
      } else {
        #pragma unroll
        for (int mi = 0; mi < 2; ++mi)
          #pragma unroll
          for (int ni = 0; ni < 4; ++ni)
            acc[mi][ni] = __builtin_amdgcn_mfma_f32_16x16x32_bf16(
                bfr[ni], af[mi], acc[mi][ni], 0, 0, 0);
      }
    }
    // ---- epilogue at end of each jq
    if (ks == 3) {
      if (jq < 2) {
        // D[j, i]: col(l16)=j, row(quad*4+reg)=i -> kt[j][i] packed in i
        #pragma unroll
        for (int ni = 0; ni < 4; ++ni) {
          int j = jq * 128 + wj + ni * 16 + l16;
          #pragma unroll
          for (int mi = 0; mi < 2; ++mi) {
            long ib = i0 + wi + mi * 16 + quad * 4;
            ushort4 u;
            u.x = f2bf(acc[mi][ni][0]);
            u.y = f2bf(acc[mi][ni][1]);
            u.z = f2bf(acc[mi][ni][2]);
            u.w = f2bf(acc[mi][ni][3]);
            *(ushort4*)&kt[(long)j * 131072 + ib] = u;
          }
        }
      } else {
        // swapped: col(l16)=i, row(quad*4+reg)=s -> v[i][s] packed in s
        #pragma unroll
        for (int mi = 0; mi < 2; ++mi) {
          long i = i0 + wi + mi * 16 + l16;
          #pragma unroll
          for (int ni = 0; ni < 4; ++ni) {
            int sb = (jq - 2) * 128 + wj + ni * 16 + quad * 4;
            ushort4 u;
            u.x = f2bf(acc[mi][ni][0]);
            u.y = f2bf(acc[mi][ni][1]);
            u.z = f2bf(acc[mi][ni][2]);
            u.w = f2bf(acc[mi][ni][3]);
            *(ushort4*)&vbuf[i * 256 + sb] = u;
          }
        }
      }
      #pragma unroll
      for (int a = 0; a < 2; ++a)
        #pragma unroll
        for (int b = 0; b < 4; ++b) acc[a][b] = (f32x4){0.f, 0.f, 0.f, 0.f};
    }
    __syncthreads();
  }
}

// ----------------------------------------------------- q projection (iter 0)
__global__ __launch_bounds__(256) void qproj_kernel(
    const float* __restrict__ slots, const float* __restrict__ gs,
    const float* __restrict__ bs, const short* __restrict__ Wqb,
    float* __restrict__ qout) {
  __shared__ float lnq[256];
  __shared__ float red[8];
  int row = blockIdx.x, t = threadIdx.x;
  int w = t >> 6, lane = t & 63;
  float x = slots[(long)row * 256 + t];
  float s = x, s2 = x * x;
  #pragma unroll
  for (int off = 32; off > 0; off >>= 1) {
    s += __shfl_xor(s, off);
    s2 += __shfl_xor(s2, off);
  }
  if (lane == 0) { red[w * 2] = s; red[w * 2 + 1] = s2; }
  __syncthreads();
  float st = red[0] + red[2] + red[4] + red[6];
  float st2 = red[1] + red[3] + red[5] + red[7];
  float mu = st * (1.f / 256.f);
  float rs = rsqrtf(st2 * (1.f / 256.f) - mu * mu + LN_EPS);
  lnq[t] = (x - mu) * rs * gs[t] + bs[t];
  __syncthreads();
  float acc = 0.f;
  for (int k = 0; k < 256; ++k)
    acc += lnq[k] * bf2f((u16)Wqb[k * 256 + t]);
  qout[(long)row * 256 + t] = acc;
}

// --------------------------------------- fused attention softmax + updates
// Block covers 512 n of one batch (grid (8,32)). Phase 1: thread = 2 n ->
// logits via u32 kt loads, softmax over 11 slots in-registers, p -> LDS +
// per-wave sums atomics (+ attn out on last iter). Phase 2: thread =
// (s-pair, n-half); UNNORMALIZED accumulation, nh-merged in LDS, one atomic
// per (kk, s) into upd (slot_step divides by sums+EPS).
__global__ __launch_bounds__(256) void attn_upd(
    const float* __restrict__ q, const short* __restrict__ kt,
    const short* __restrict__ vb, float* __restrict__ attn_out,
    float* __restrict__ sums, float* __restrict__ upd, int emit_attn) {
  __shared__ float qs[3072];      // [f][12] (phase 1) / merge buf (phase 2)
  __shared__ float ps[11 * 512];  // [kk][n]
  int b = blockIdx.y;
  int n0 = blockIdx.x * 512;
  int t = threadIdx.x, lane = t & 63;
  for (int e = t; e < 2816; e += 256) {
    int kk = e >> 8, f = e & 255;
    qs[f * 12 + kk] = q[b * 2816 + e];
  }
  __syncthreads();
  long base = (long)b * 4096 + n0 + 2 * t;
  float a0[11], a1[11];
  #pragma unroll
  for (int kk = 0; kk < 11; ++kk) { a0[kk] = 0.f; a1[kk] = 0.f; }
  for (int f = 0; f < 256; ++f) {
    u32 u = *(const u32*)(kt + (long)f * 131072 + base);
    float k0 = bf2f((u16)(u & 0xffffu));
    float k1 = bf2f((u16)(u >> 16));
    float4 qa = *(const float4*)&qs[f * 12];
    float4 qb4 = *(const float4*)&qs[f * 12 + 4];
    float4 qc = *(const float4*)&qs[f * 12 + 8];
    a0[0] += k0 * qa.x;  a1[0] += k1 * qa.x;
    a0[1] += k0 * qa.y;  a1[1] += k1 * qa.y;
    a0[2] += k0 * qa.z;  a1[2] += k1 * qa.z;
    a0[3] += k0 * qa.w;  a1[3] += k1 * qa.w;
    a0[4] += k0 * qb4.x; a1[4] += k1 * qb4.x;
    a0[5] += k0 * qb4.y; a1[5] += k1 * qb4.y;
    a0[6] += k0 * qb4.z; a1[6] += k1 * qb4.z;
    a0[7] += k0 * qb4.w; a1[7] += k1 * qb4.w;
    a0[8] += k0 * qc.x;  a1[8] += k1 * qc.x;
    a0[9] += k0 * qc.y;  a1[9] += k1 * qc.y;
    a0[10] += k0 * qc.z; a1[10] += k1 * qc.z;
  }
  float m0 = -1e30f, m1 = -1e30f;
  #pragma unroll
  for (int kk = 0; kk < 11; ++kk) {
    a0[kk] *= 0.0625f;  // 256^-0.5
    a1[kk] *= 0.0625f;
    m0 = fmaxf(m0, a0[kk]);
    m1 = fmaxf(m1, a1[kk]);
  }
  float s0 = 0.f, s1 = 0.f;
  #pragma unroll
  for (int kk = 0; kk < 11; ++kk) {
    a0[kk] = expf(a0[kk] - m0);
    a1[kk] = expf(a1[kk] - m1);
    s0 += a0[kk];
    s1 += a1[kk];
  }
  float i0 = 1.0f / s0, i1 = 1.0f / s1;
  #pragma unroll
  for (int kk = 0; kk < 11; ++kk) {
    float p0 = a0[kk] * i0, p1 = a1[kk] * i1;
    *(float2*)&ps[kk * 512 + 2 * t] = make_float2(p0, p1);
    if (emit_attn)
      *(float2*)(attn_out + ((long)b * 11 + kk) * 4096 + n0 + 2 * t) =
          make_float2(p0, p1);
    float sv = p0 + p1;
    #pragma unroll
    for (int off = 32; off > 0; off >>= 1) sv += __shfl_xor(sv, off);
    if (lane == 0) atomicAdd(&sums[b * 11 + kk], sv);
  }
  __syncthreads();
  // ---- phase 2: thread = (s-pair sp, n-half nh)
  int sp = t & 127, nh = t >> 7;
  float2 acc[11];
  #pragma unroll
  for (int kk = 0; kk < 11; ++kk) acc[kk] = make_float2(0.f, 0.f);
  const u32* vb2 =
      (const u32*)(vb + ((long)b * 4096 + n0 + nh * 256) * 256);
  int pbase = nh * 256;
  for (int n4 = 0; n4 < 256; n4 += 4) {
    u32 u0 = vb2[(n4 + 0) * 128 + sp];
    u32 u1 = vb2[(n4 + 1) * 128 + sp];
    u32 u2 = vb2[(n4 + 2) * 128 + sp];
    u32 u3 = vb2[(n4 + 3) * 128 + sp];
    float v0x = bf2f((u16)(u0 & 0xffffu)), v0y = bf2f((u16)(u0 >> 16));
    float v1x = bf2f((u16)(u1 & 0xffffu)), v1y = bf2f((u16)(u1 >> 16));
    float v2x = bf2f((u16)(u2 & 0xffffu)), v2y = bf2f((u16)(u2 >> 16));
    float v3x = bf2f((u16)(u3 & 0xffffu)), v3y = bf2f((u16)(u3 >> 16));
    #pragma unroll
    for (int kk = 0; kk < 11; ++kk) {
      float4 a4 = *(const float4*)&ps[kk * 512 + pbase + n4];
      acc[kk].x += a4.x * v0x + a4.y * v1x + a4.z * v2x + a4.w * v3x;
      acc[kk].y += a4.x * v0y + a4.y * v1y + a4.z * v2y + a4.w * v3y;
    }
  }
  // merge nh=1 into nh=0 via LDS (reuse qs: 11*256 = 2816 floats)
  __syncthreads();
  if (nh == 1) {
    #pragma unroll
    for (int kk = 0; kk < 11; ++kk) {
      qs[kk * 256 + 2 * sp] = acc[kk].x;
      qs[kk * 256 + 2 * sp + 1] = acc[kk].y;
    }
  }
  __syncthreads();
  if (nh == 0) {
    #pragma unroll
    for (int kk = 0; kk < 11; ++kk) {
      atomicAdd(&upd[((long)b * 11 + kk) * 256 + 2 * sp],
                acc[kk].x + qs[kk * 256 + 2 * sp]);
      atomicAdd(&upd[((long)b * 11 + kk) * 256 + 2 * sp + 1],
                acc[kk].y + qs[kk * 256 + 2 * sp + 1]);
    }
  }
}

// -------------------------------------------- fused slot step (2 rows/block)
// slots' = GRU(upd/(sums+EPS), slots); out = slots' + MLP(LN(slots'));
// optional q = LN(out)@Wq for next iter. Zeroes its own upd/sums rows for
// the next iteration's atomics.
__global__ __launch_bounds__(256) void slot_step(
    float* __restrict__ upd, float* __restrict__ sums,
    const float* __restrict__ slots_in,
    const float* __restrict__ wihT, const float* __restrict__ whhT,
    const float* __restrict__ b_ih, const float* __restrict__ b_hh,
    const float* __restrict__ gm, const float* __restrict__ bm,
    const short* __restrict__ W1b, const float* __restrict__ b1,
    const short* __restrict__ W2b, const float* __restrict__ b2,
    const float* __restrict__ gs, const float* __restrict__ bs,
    const short* __restrict__ Wqb,
    float* __restrict__ slots_out, float* __restrict__ qout, int emit_q) {
  __shared__ float xs[2][256], hs[2][256], sgv[2][256], ln1[2][256];
  __shared__ float giv[2][768], ghv[2][768];
  __shared__ float h1v[2][1024];
  __shared__ float pw2[4][2][256];
  __shared__ float red[2][2];
  int t = threadIdx.x;
  int w = t >> 6, lane = t & 63;
  int r0 = blockIdx.x * 2;
  #pragma unroll
  for (int row = 0; row < 2; ++row) {
    int r = r0 + row;
    float sc = 1.0f / (sums[r] + EPS);
    xs[row][t] = upd[(long)r * 256 + t] * sc;
    hs[row][t] = slots_in[(long)r * 256 + t];
  }
  __syncthreads();
  // zero own rows of upd/sums for next iteration (all reads done above)
  #pragma unroll
  for (int row = 0; row < 2; ++row) {
    upd[(long)(r0 + row) * 256 + t] = 0.f;
    if (t == row) sums[r0 + row] = 0.f;
  }
  // ---- GRU gemms: thread = 3 cols {t, t+256, t+512}
  {
    float accI[2][3] = {}, accH[2][3] = {};
    for (int k = 0; k < 256; ++k) {
      float x0 = xs[0][k], x1 = xs[1][k];
      float h0 = hs[0][k], h1 = hs[1][k];
      #pragma unroll
      for (int j = 0; j < 3; ++j) {
        float wI = wihT[k * 768 + j * 256 + t];
        float wH = whhT[k * 768 + j * 256 + t];
        accI[0][j] += x0 * wI; accI[1][j] += x1 * wI;
        accH[0][j] += h0 * wH; accH[1][j] += h1 * wH;
      }
    }
    #pragma unroll
    for (int row = 0; row < 2; ++row)
      #pragma unroll
      for (int j = 0; j < 3; ++j) {
        giv[row][j * 256 + t] = accI[row][j] + b_ih[j * 256 + t];
        ghv[row][j * 256 + t] = accH[row][j] + b_hh[j * 256 + t];
      }
  }
  __syncthreads();
  // ---- GRU gates
  #pragma unroll
  for (int row = 0; row < 2; ++row) {
    float irv = giv[row][t], izv = giv[row][256 + t], inv = giv[row][512 + t];
    float hrv = ghv[row][t], hzv = ghv[row][256 + t], hnv = ghv[row][512 + t];
    float hv = hs[row][t];
    float rg = 1.f / (1.f + expf(-(irv + hrv)));
    float zg = 1.f / (1.f + expf(-(izv + hzv)));
    float ng = tanhf(inv + rg * hnv);
    sgv[row][t] = (1.f - zg) * ng + zg * hv;
  }
  __syncthreads();
  // ---- LN(gm,bm)
  if (w < 2) {
    float4 sv = *(const float4*)&sgv[w][lane * 4];
    float s = sv.x + sv.y + sv.z + sv.w;
    float s2 = sv.x * sv.x + sv.y * sv.y + sv.z * sv.z + sv.w * sv.w;
    #pragma unroll
    for (int off = 32; off > 0; off >>= 1) {
      s += __shfl_xor(s, off);
      s2 += __shfl_xor(s2, off);
    }
    if (lane == 0) {
      float mu = s * (1.f / 256.f);
      red[w][0] = mu;
      red[w][1] = rsqrtf(s2 * (1.f / 256.f) - mu * mu + LN_EPS);
    }
  }
  __syncthreads();
  #pragma unroll
  for (int row = 0; row < 2; ++row)
    ln1[row][t] = (sgv[row][t] - red[row][0]) * red[row][1] * gm[t] + bm[t];
  __syncthreads();
  // ---- W1 + relu: thread = 4 cols of 1024
  {
    float acc1[2][4] = {};
    for (int k = 0; k < 256; ++k) {
      ushort4 w4 = *(const ushort4*)(W1b + (long)k * 1024 + 4 * t);
      float wv[4] = {bf2f(w4.x), bf2f(w4.y), bf2f(w4.z), bf2f(w4.w)};
      float l0 = ln1[0][k], l1 = ln1[1][k];
      #pragma unroll
      for (int j = 0; j < 4; ++j) {
        acc1[0][j] += l0 * wv[j];
        acc1[1][j] += l1 * wv[j];
      }
    }
    #pragma unroll
    for (int row = 0; row < 2; ++row)
      #pragma unroll
      for (int j = 0; j < 4; ++j)
        h1v[row][4 * t + j] = fmaxf(acc1[row][j] + b1[4 * t + j], 0.f);
  }
  __syncthreads();
  // ---- W2: k-split across waves (wave w -> k in [w*256, w*256+256))
  {
    float acc2[2][4] = {};
    int kbase = w * 256;
    for (int kk = 0; kk < 256; ++kk) {
      int k = kbase + kk;
      ushort4 w4 = *(const ushort4*)(W2b + (long)k * 256 + 4 * lane);
      float wv[4] = {bf2f(w4.x), bf2f(w4.y), bf2f(w4.z), bf2f(w4.w)};
      float h0 = h1v[0][k], h1 = h1v[1][k];
      #pragma unroll
      for (int j = 0; j < 4; ++j) {
        acc2[0][j] += h0 * wv[j];
        acc2[1][j] += h1 * wv[j];
      }
    }
    #pragma unroll
    for (int row = 0; row < 2; ++row)
      #pragma unroll
      for (int j = 0; j < 4; ++j) pw2[w][row][4 * lane + j] = acc2[row][j];
  }
  __syncthreads();
  float outv[2];
  #pragma unroll
  for (int row = 0; row < 2; ++row) {
    float s = pw2[0][row][t] + pw2[1][row][t] + pw2[2][row][t] + pw2[3][row][t];
    outv[row] = s + b2[t] + sgv[row][t];
    slots_out[(long)(r0 + row) * 256 + t] = outv[row];
  }
  // ---- q for next iteration
  if (emit_q) {
    __syncthreads();
    xs[0][t] = outv[0];
    xs[1][t] = outv[1];
    __syncthreads();
    if (w < 2) {
      float4 sv = *(const float4*)&xs[w][lane * 4];
      float s = sv.x + sv.y + sv.z + sv.w;
      float s2 = sv.x * sv.x + sv.y * sv.y + sv.z * sv.z + sv.w * sv.w;
      #pragma unroll
      for (int off = 32; off > 0; off >>= 1) {
        s += __shfl_xor(s, off);
        s2 += __shfl_xor(s2, off);
      }
      if (lane == 0) {
        float mu = s * (1.f / 256.f);
        red[w][0] = mu;
        red[w][1] = rsqrtf(s2 * (1.f / 256.f) - mu * mu + LN_EPS);
      }
    }
    __syncthreads();
    #pragma unroll
    for (int row = 0; row < 2; ++row)
      hs[row][t] = (xs[row][t] - red[row][0]) * red[row][1] * gs[t] + bs[t];
    __syncthreads();
    float accq[2] = {};
    for (int k = 0; k < 256; ++k) {
      float wq = bf2f((u16)Wqb[k * 256 + t]);
      accq[0] += hs[0][k] * wq;
      accq[1] += hs[1][k] * wq;
    }
    #pragma unroll
    for (int row = 0; row < 2; ++row)
      qout[(long)(r0 + row) * 256 + t] = accq[row];
  }
}

// ---------------------------------------------------------------- launcher
extern "C" void kernel_launch(void* const* d_in, const int* in_sizes, int n_in,
                              void* d_out, int out_size, void* d_ws,
                              size_t ws_size, hipStream_t stream) {
  const float* features = (const float*)d_in[0];
  const float* sigma = (const float*)d_in[1];
  const float* z = (const float*)d_in[2];
  const float* slots_init_w = (const float*)d_in[3];
  const float* gf = (const float*)d_in[4];
  const float* bf = (const float*)d_in[5];
  const float* gs = (const float*)d_in[6];
  const float* bs = (const float*)d_in[7];
  const float* gm = (const float*)d_in[8];
  const float* bm = (const float*)d_in[9];
  const float* Wk = (const float*)d_in[10];
  const float* Wv = (const float*)d_in[11];
  const float* Wq = (const float*)d_in[12];
  const float* W_ih = (const float*)d_in[13];
  const float* W_hh = (const float*)d_in[14];
  const float* b_ih = (const float*)d_in[15];
  const float* b_hh = (const float*)d_in[16];
  const float* W1 = (const float*)d_in[17];
  const float* b1 = (const float*)d_in[18];
  const float* W2 = (const float*)d_in[19];
  const float* b2 = (const float*)d_in[20];

  float* ws = (float*)d_ws;
  size_t o = 0;
  short* ktb = (short*)(ws + o); o += 16777216;   // 256 x 131072 bf16
  short* vbuf = (short*)(ws + o); o += 16777216;  // 131072 x 256 bf16
  short* Btb = (short*)(ws + o); o += 65536;      // 512 x 256 bf16
  float* wihT = ws + o; o += 196608;              // fp32 [256][768]
  float* whhT = ws + o; o += 196608;
  short* W1b = (short*)(ws + o); o += 131072;     // 256x1024 bf16
  short* W2b = (short*)(ws + o); o += 131072;     // 1024x256 bf16
  short* Wqb = (short*)(ws + o); o += 32768;      // 256x256 bf16
  float* slots = ws + o; o += 90112;
  float* qbuf = ws + o; o += 90112;
  float* upd = ws + o; o += 90112;
  float* sums = ws + o; o += 352;

  float* out_slots = (float*)d_out;
  float* out_attn = (float*)d_out + 90112;

  init_slots_kernel<<<352, 256, 0, stream>>>(slots_init_w, z, sigma, slots,
                                             upd, sums);
  wprep_kernel<<<4352, 256, 0, stream>>>(W_ih, W_hh, W1, W2, Wq, Wk, Wv,
                                         wihT, whhT, W1b, W2b, Wqb, Btb);
  gemm_kv<<<2048, 256, 0, stream>>>(features, Btb, gf, bf, ktb, vbuf);
  qproj_kernel<<<352, 256, 0, stream>>>(slots, gs, bs, Wqb, qbuf);

  for (int it = 0; it < 3; ++it) {
    attn_upd<<<dim3(8, 32), 256, 0, stream>>>(
        qbuf, ktb, vbuf, out_attn, sums, upd, (it == 2) ? 1 : 0);
    slot_step<<<176, 256, 0, stream>>>(
        upd, sums, slots, wihT, whhT, b_ih, b_hh, gm, bm, W1b, b1, W2b, b2,
        gs, bs, Wqb, (it == 2) ? out_slots : slots, qbuf, (it < 2) ? 1 : 0);
  }
}